// Round 1
// baseline (1485.224 us; speedup 1.0000x reference)
//
#include <hip/hip_runtime.h>

// HeaNet: SchNet-like GNN on MI355X.
// N=8192 nodes, B=32 graphs, E=131072 edges, H=F=128, G=50 gaussians, L=6 layers,
// NC=160 components. All 6 layers are independent (h fixed, types only accumulates).
// Edge messages are aggregated directly into comp[NC,128] (node-level agg is
// immediately component-summed in the reference, so it's skippable).
// Edges are counting-sorted by comp_id(dst) once so waves are cid-uniform ->
// shuffle-reduce + 1 atomic per feature.

#define NNODES 8192
#define NGRAPH 32
#define NPER   256
#define NELEM  5
#define NEDGE  131072
#define HD     128
#define FD     128
#define GD     50
#define LL     6
#define NC     160
#define CUT    10.0f
#define LOG2_  0.69314718055994531f

__device__ __forceinline__ float ssp(float x) {
    // softplus(x) - log(2), numerically stable
    float m = fmaxf(x, 0.0f);
    float z = __expf(-fabsf(x));
    return m + __logf(1.0f + z) - LOG2_;
}

// ---------- setup kernels (layer-invariant) ----------

__global__ void hist_edges(const int* __restrict__ ei, const int* __restrict__ comp_id,
                           int* __restrict__ hist) {
    __shared__ int lh[NC];
    int tid = threadIdx.x;
    if (tid < NC) lh[tid] = 0;
    __syncthreads();
    int e = blockIdx.x * 256 + tid;
    int dst = ei[NEDGE + e];
    atomicAdd(&lh[comp_id[dst]], 1);
    __syncthreads();
    if (tid < NC) atomicAdd(&hist[tid], lh[tid]);
}

__global__ void count_nodes(const int* __restrict__ comp_id, int* __restrict__ counts) {
    int n = blockIdx.x * 256 + threadIdx.x;
    atomicAdd(&counts[comp_id[n]], 1);
}

__global__ void scan_offsets(const int* __restrict__ hist, const int* __restrict__ counts,
                             int* __restrict__ cursor, float* __restrict__ countsf) {
    if (threadIdx.x == 0) {
        int run = 0;
        for (int c = 0; c < NC; ++c) { cursor[c] = run; run += hist[c]; }
    }
    if (threadIdx.x < NC) countsf[threadIdx.x] = (float)counts[threadIdx.x];
}

__global__ void scatter_edges(const float* __restrict__ pos, const int* __restrict__ ei,
                              const int* __restrict__ comp_id, int* __restrict__ cursor,
                              float* __restrict__ ew_s, float* __restrict__ c_s,
                              int* __restrict__ src_s, int* __restrict__ cid_s) {
    int e = blockIdx.x * 256 + threadIdx.x;
    int s = ei[e], d = ei[NEDGE + e];
    float dx = pos[3*s]   - pos[3*d];
    float dy = pos[3*s+1] - pos[3*d+1];
    float dz = pos[3*s+2] - pos[3*d+2];
    float d2 = dx*dx + dy*dy + dz*dz;
    float ew = sqrtf(d2);
    float C  = CUT / (1e-10f + d2) - 1.0f;
    int cid = comp_id[d];
    int idx = atomicAdd(&cursor[cid], 1);
    ew_s[idx] = ew; c_s[idx] = C; src_s[idx] = s; cid_s[idx] = cid;
}

__global__ void transpose_w2(const float* __restrict__ w2, float* __restrict__ w2t) {
    int idx = blockIdx.x * 256 + threadIdx.x;     // over 6*128*128
    int l = idx >> 14; int r = idx & 16383;
    int fo = r >> 7;   int fi = r & 127;
    w2t[idx] = w2[(l << 14) + (fi << 7) + fo];
}

// xh_all[l][n][f] = (emb[z[n]] @ cf_lin1_w[l])[f]
__global__ __launch_bounds__(256) void xh_kernel(const float* __restrict__ emb,
                                                 const int* __restrict__ z,
                                                 const float* __restrict__ cf1,
                                                 float* __restrict__ xh_all) {
    int l = blockIdx.y;
    int n = blockIdx.x * 256 + threadIdx.x;
    const float* h = emb + z[n] * HD;
    const float* w = cf1 + l * HD * FD;
    float acc[FD];
    #pragma unroll
    for (int f = 0; f < FD; ++f) acc[f] = 0.0f;
    #pragma unroll 1
    for (int k = 0; k < HD; ++k) {
        float hk = h[k];
        const float* wk = w + k * FD;
        #pragma unroll
        for (int f = 0; f < FD; ++f) acc[f] = fmaf(hk, wk[f], acc[f]);
    }
    float* o = xh_all + ((long)l * NNODES + n) * FD;
    #pragma unroll
    for (int f = 0; f < FD; f += 4)
        *(float4*)(o + f) = make_float4(acc[f], acc[f+1], acc[f+2], acc[f+3]);
}

__global__ void types_init(const float* __restrict__ emb, const int* __restrict__ comps_z,
                           float* __restrict__ types) {
    int c = blockIdx.x; int f = threadIdx.x;
    types[c * HD + f] = emb[comps_z[c] * HD + f];
}

// ---------- the hot kernel: per-edge filter MLP + message + comp aggregation ----------
// Thread = one (sorted) edge. t[128] lives in VGPRs; W1/W2t/b read via wave-uniform
// addresses (scalarized to s_load broadcasts). grid=(E/256, L).
__global__ __launch_bounds__(256) void edge_kernel(
    const float* __restrict__ ew_s, const float* __restrict__ c_s,
    const int* __restrict__ src_s, const int* __restrict__ cid_s,
    const float* __restrict__ w1_, const float* __restrict__ b1_,
    const float* __restrict__ w2t_, const float* __restrict__ b2_,
    const float* __restrict__ xh_all, float* __restrict__ comp_acc)
{
    int l = blockIdx.y;
    int e = blockIdx.x * 256 + threadIdx.x;
    int lane = threadIdx.x & 63;
    float ew = ew_s[e];
    float Ce = c_s[e];
    int src  = src_s[e];
    int cid  = cid_s[e];
    const float* w1 = w1_ + l * GD * FD;
    const float* b1 = b1_ + l * FD;
    const float* w2 = w2t_ + l * FD * FD;     // [fo][fi]
    const float* b2 = b2_ + l * FD;
    const float* xh = xh_all + ((long)l * NNODES + src) * FD;
    float* cacc = comp_acc + (l * NC + cid) * FD;

    // stage 1: t = ssp(edge_attr @ W1 + b1); gaussians recomputed per g (no LDS)
    float t[FD];
    #pragma unroll
    for (int f = 0; f < FD; ++f) t[f] = b1[f];
    const float delta = CUT / (GD - 1);
    const float coeff = -0.5f / (delta * delta);
    #pragma unroll 1
    for (int g = 0; g < GD; ++g) {
        float dd = ew - g * delta;
        float a = __expf(coeff * dd * dd);
        const float* w1g = w1 + g * FD;
        #pragma unroll
        for (int f = 0; f < FD; ++f) t[f] = fmaf(a, w1g[f], t[f]);
    }
    #pragma unroll
    for (int f = 0; f < FD; ++f) t[f] = ssp(t[f]);

    int c0 = __shfl(cid, 0);
    bool uni = (__all(cid == c0) != 0);

    // stage 2+3: W = (t @ W2 + b2) * C; msg = xh[src] * W; reduce into comp
    #pragma unroll 1
    for (int fo = 0; fo < FD; fo += 4) {
        float a0 = b2[fo], a1 = b2[fo+1], a2 = b2[fo+2], a3 = b2[fo+3];
        const float* r0 = w2 + (fo    ) * FD;
        const float* r1 = w2 + (fo + 1) * FD;
        const float* r2 = w2 + (fo + 2) * FD;
        const float* r3 = w2 + (fo + 3) * FD;
        #pragma unroll
        for (int fi = 0; fi < FD; ++fi) {
            float tv = t[fi];
            a0 = fmaf(tv, r0[fi], a0);
            a1 = fmaf(tv, r1[fi], a1);
            a2 = fmaf(tv, r2[fi], a2);
            a3 = fmaf(tv, r3[fi], a3);
        }
        float4 xv = *(const float4*)(xh + fo);
        float m0 = xv.x * (a0 * Ce);
        float m1 = xv.y * (a1 * Ce);
        float m2 = xv.z * (a2 * Ce);
        float m3 = xv.w * (a3 * Ce);
        if (uni) {
            #pragma unroll
            for (int s = 32; s > 0; s >>= 1) {
                m0 += __shfl_xor(m0, s);
                m1 += __shfl_xor(m1, s);
                m2 += __shfl_xor(m2, s);
                m3 += __shfl_xor(m3, s);
            }
            if (lane == 0) {
                atomicAdd(&cacc[fo],     m0);
                atomicAdd(&cacc[fo + 1], m1);
                atomicAdd(&cacc[fo + 2], m2);
                atomicAdd(&cacc[fo + 3], m3);
            }
        } else {
            atomicAdd(&cacc[fo],     m0);
            atomicAdd(&cacc[fo + 1], m1);
            atomicAdd(&cacc[fo + 2], m2);
            atomicAdd(&cacc[fo + 3], m3);
        }
    }
}

// ---------- per-component update: x = ssp(comp@cf2+b)@intw+b; types += x ----------
__global__ __launch_bounds__(128) void comp_kernel(
    const float* __restrict__ comp_acc, const float* __restrict__ countsf,
    const float* __restrict__ cf2w, const float* __restrict__ cf2b,
    const float* __restrict__ intw, const float* __restrict__ intb,
    float* __restrict__ types)
{
    int c = blockIdx.x, l = blockIdx.y, f = threadIdx.x;
    __shared__ float comp[FD];
    __shared__ float sx[FD];
    comp[f] = comp_acc[(l * NC + c) * FD + f] / countsf[c];
    __syncthreads();
    float acc = cf2b[l * HD + f];
    const float* w = cf2w + l * FD * HD;
    #pragma unroll 1
    for (int k = 0; k < FD; ++k) acc = fmaf(comp[k], w[k * HD + f], acc);
    sx[f] = ssp(acc);
    __syncthreads();
    float acc2 = intb[l * HD + f];
    const float* wi = intw + l * HD * HD;
    #pragma unroll 1
    for (int k = 0; k < HD; ++k) acc2 = fmaf(sx[k], wi[k * HD + f], acc2);
    atomicAdd(&types[c * HD + f], acc2);
}

// ---------- readout: out[b] = sum_c per_comp(c),  per_comp = ssp(types@w1+b1)@w2+b2 ----------
__global__ __launch_bounds__(64) void readout_kernel(
    const float* __restrict__ types, const float* __restrict__ w1,
    const float* __restrict__ b1, const float* __restrict__ w2,
    const float* __restrict__ b2, float* __restrict__ out)
{
    int b = blockIdx.x, lane = threadIdx.x;
    float sum = 0.0f;
    for (int cc = 0; cc < NELEM; ++cc) {
        int c = b * NELEM + cc;
        float acc = b1[lane];
        const float* tr = types + c * HD;
        #pragma unroll 1
        for (int k = 0; k < HD; ++k) acc = fmaf(tr[k], w1[k * 64 + lane], acc);
        sum += ssp(acc) * w2[lane];
    }
    #pragma unroll
    for (int s = 32; s > 0; s >>= 1) sum += __shfl_xor(sum, s);
    if (lane == 0) out[b] = sum + (float)NELEM * b2[0];
}

extern "C" void kernel_launch(void* const* d_in, const int* in_sizes, int n_in,
                              void* d_out, int out_size, void* d_ws, size_t ws_size,
                              hipStream_t stream) {
    (void)in_sizes; (void)n_in; (void)out_size; (void)ws_size;
    const float* pos     = (const float*)d_in[0];
    const float* emb     = (const float*)d_in[1];
    const float* mlp_w1  = (const float*)d_in[2];
    const float* mlp_b1  = (const float*)d_in[3];
    const float* mlp_w2  = (const float*)d_in[4];
    const float* mlp_b2  = (const float*)d_in[5];
    const float* cf1     = (const float*)d_in[6];
    const float* cf2w    = (const float*)d_in[7];
    const float* cf2b    = (const float*)d_in[8];
    const float* intw    = (const float*)d_in[9];
    const float* intb    = (const float*)d_in[10];
    const float* ow1     = (const float*)d_in[11];
    const float* ob1     = (const float*)d_in[12];
    const float* ow2     = (const float*)d_in[13];
    const float* ob2     = (const float*)d_in[14];
    const int*   z       = (const int*)d_in[15];
    const int*   comp_id = (const int*)d_in[16];
    const int*   ei      = (const int*)d_in[17];
    const int*   comps_z = (const int*)d_in[18];
    float* out = (float*)d_out;

    char* ws = (char*)d_ws;
    size_t off = 0;
    auto alloc = [&](size_t bytes) -> void* {
        void* p = ws + off;
        off += (bytes + 255) & ~(size_t)255;
        return p;
    };
    // zeroed prefix: comp_acc | hist | counts
    float* comp_acc = (float*)alloc((size_t)LL * NC * FD * 4);
    int*   hist     = (int*)  alloc(NC * 4);
    int*   counts   = (int*)  alloc(NC * 4);
    size_t zero_bytes = off;
    int*   cursor   = (int*)  alloc(NC * 4);
    float* countsf  = (float*)alloc(NC * 4);
    float* ew_s     = (float*)alloc((size_t)NEDGE * 4);
    float* c_s      = (float*)alloc((size_t)NEDGE * 4);
    int*   src_s    = (int*)  alloc((size_t)NEDGE * 4);
    int*   cid_s    = (int*)  alloc((size_t)NEDGE * 4);
    float* w2t      = (float*)alloc((size_t)LL * FD * FD * 4);
    float* xh_all   = (float*)alloc((size_t)LL * NNODES * FD * 4);
    float* types    = (float*)alloc((size_t)NC * HD * 4);

    hipMemsetAsync(d_ws, 0, zero_bytes, stream);

    hist_edges   <<<NEDGE / 256, 256, 0, stream>>>(ei, comp_id, hist);
    count_nodes  <<<NNODES / 256, 256, 0, stream>>>(comp_id, counts);
    scan_offsets <<<1, 256, 0, stream>>>(hist, counts, cursor, countsf);
    scatter_edges<<<NEDGE / 256, 256, 0, stream>>>(pos, ei, comp_id, cursor,
                                                   ew_s, c_s, src_s, cid_s);
    transpose_w2 <<<(LL * FD * FD) / 256, 256, 0, stream>>>(mlp_w2, w2t);
    xh_kernel    <<<dim3(NNODES / 256, LL), 256, 0, stream>>>(emb, z, cf1, xh_all);
    types_init   <<<NC, HD, 0, stream>>>(emb, comps_z, types);
    edge_kernel  <<<dim3(NEDGE / 256, LL), 256, 0, stream>>>(ew_s, c_s, src_s, cid_s,
                                                             mlp_w1, mlp_b1, w2t, mlp_b2,
                                                             xh_all, comp_acc);
    comp_kernel  <<<dim3(NC, LL), 128, 0, stream>>>(comp_acc, countsf, cf2w, cf2b,
                                                    intw, intb, types);
    readout_kernel<<<NGRAPH, 64, 0, stream>>>(types, ow1, ob1, ow2, ob2, out);
}